// Round 2
// baseline (5273.006 us; speedup 1.0000x reference)
//
#include <hip/hip_runtime.h>
#include <hip/hip_bf16.h>

// Problem constants (fixed by the reference)
#define NN  131072      // nodes
#define GG  1024        // graphs
#define NPG 128         // nodes per graph
#define EE  4194304     // edges
#define DD  128         // input feature dim
#define CC  32          // per-layer conv width

typedef __hip_bfloat16 bf16;

// ---- dtype probe: classify x0's first 128 uint16s. bf16 buffer -> nearly all
// have plausible bf16 exponents; f32 buffer -> only the high halves (~54%) do.
__global__ void k_probe(const unsigned short* __restrict__ x, int* __restrict__ flag) {
    unsigned short u = x[threadIdx.x];
    int e = (u >> 7) & 0xFF;
    int q = (e >= 0x70 && e <= 0x85) ? 1 : 0;   // |v| in [2^-15, 2^6]
    unsigned long long m = __ballot(q);
    __shared__ int cnt[2];
    if ((threadIdx.x & 63) == 0) cnt[threadIdx.x >> 6] = __popcll(m);
    __syncthreads();
    if (threadIdx.x == 0) flag[0] = (cnt[0] + cnt[1] >= 96) ? 1 : 0;  // 1 = bf16 mode
}

// ---- convert a weight tensor to f32 scratch (dual dtype) ----
__global__ void k_cvt(const void* __restrict__ in, float* __restrict__ out, int n,
                      const int* __restrict__ flag) {
    int i = blockIdx.x * 256 + threadIdx.x;
    if (i >= n) return;
    if (flag[0]) out[i] = __bfloat162float(((const bf16*)in)[i]);
    else         out[i] = ((const float*)in)[i];
}

// ---- degree: deg[dst] += 1 over all edges ----
__global__ void k_deg(const int* __restrict__ ei, float* __restrict__ deg) {
    int t = blockIdx.x * 256 + threadIdx.x;
    if (t < EE) atomicAdd(&deg[ei[EE + t]], 1.0f);
}

// ---- dis = rsqrt(deg + 1) in place ----
__global__ void k_dis(float* __restrict__ deg) {
    int i = blockIdx.x * 256 + threadIdx.x;
    if (i < NN) deg[i] = rsqrtf(deg[i] + 1.0f);
}

// ---- h = x(N x 128, dtype per flag) @ W(f32 128 x 32) -> f32 N x 32 ----
__global__ void __launch_bounds__(256) k_gemm0(const void* __restrict__ x,
                                               const float* __restrict__ W,
                                               float* __restrict__ h,
                                               const int* __restrict__ flag) {
    __shared__ float Wl[DD * CC];   // 16 KB
    __shared__ float xl[8 * DD];    // 4 KB
    int tid = threadIdx.x;
    int bfm = flag[0];
    for (int t = tid; t < DD * CC; t += 256) Wl[t] = W[t];
    long rowbase = (long)blockIdx.x * 8;
    if (bfm) {
        const bf16* xp = (const bf16*)x;
        for (int t = tid; t < 8 * DD; t += 256) xl[t] = __bfloat162float(xp[rowbase * DD + t]);
    } else {
        const float* xp = (const float*)x;
        for (int t = tid; t < 8 * DD; t += 256) xl[t] = xp[rowbase * DD + t];
    }
    __syncthreads();
    int r = tid >> 5, c = tid & 31;
    float acc = 0.f;
    #pragma unroll 8
    for (int k = 0; k < DD; k++) acc += xl[r * DD + k] * Wl[k * CC + c];
    h[(rowbase + r) * CC + c] = acc;
}

// ---- h = hin(f32 N x 32) @ W(f32 32 x 32) -> f32 N x 32 ----
__global__ void __launch_bounds__(256) k_gemm32(const float* __restrict__ hin,
                                                const float* __restrict__ W,
                                                float* __restrict__ hout) {
    __shared__ float Wl[CC * CC];
    __shared__ float xl[8 * CC];
    int tid = threadIdx.x;
    for (int t = tid; t < CC * CC; t += 256) Wl[t] = W[t];
    long rowbase = (long)blockIdx.x * 8;
    for (int t = tid; t < 8 * CC; t += 256) xl[t] = hin[rowbase * CC + t];
    __syncthreads();
    int r = tid >> 5, c = tid & 31;
    float acc = 0.f;
    #pragma unroll
    for (int k = 0; k < CC; k++) acc += xl[r * CC + k] * Wl[k * CC + c];
    hout[(rowbase + r) * CC + c] = acc;
}

// ---- agg[dst] += h[src] * dis[src]*dis[dst] over all edges ----
__global__ void __launch_bounds__(256) k_agg(const int* __restrict__ ei,
                                             const float* __restrict__ dis,
                                             const float* __restrict__ h,
                                             float* __restrict__ agg) {
    long t = (long)blockIdx.x * 256 + threadIdx.x;   // t < EE*32, exact multiple
    int e = (int)(t >> 5);
    int j = (int)(t & 31);
    int s = ei[e];
    int d = ei[EE + e];
    float w = dis[s] * dis[d];
    atomicAdd(&agg[(long)d * CC + j], h[(long)s * CC + j] * w);
}

// ---- out = tanh(agg + h*dis^2 + bias); stash seed rows into cat ----
__global__ void __launch_bounds__(256) k_final(float* __restrict__ agg,
                                               const float* __restrict__ h,
                                               const float* __restrict__ dis,
                                               const float* __restrict__ bias,
                                               float* __restrict__ cat, int boff) {
    int i = blockIdx.x * 256 + threadIdx.x;   // < NN*CC
    int node = i >> 5, j = i & 31;
    float di = dis[node];
    float v = agg[i] + h[i] * di * di + bias[j];
    v = tanhf(v);
    agg[i] = v;
    if ((node & (NPG - 1)) == 0)
        cat[(node >> 7) * 288 + boff + j] = v;
}

// ---- head: hidden = cat @ W1 + b1 ; feature ; log_softmax ; loss/acc partials ----
__global__ void __launch_bounds__(128) k_head(const float* __restrict__ cat,
                                              const float* __restrict__ W1,
                                              const float* __restrict__ b1,
                                              const float* __restrict__ W2,
                                              const float* __restrict__ b2,
                                              const int* __restrict__ y,
                                              void* __restrict__ out,
                                              float* __restrict__ scal,
                                              const int* __restrict__ flag) {
    __shared__ float crow[288];
    __shared__ float red[4];
    int g = blockIdx.x, tid = threadIdx.x;
    int bfm = flag[0];
    for (int t = tid; t < 288; t += 128) crow[t] = cat[g * 288 + t];
    __syncthreads();
    float acc = 0.f;
    #pragma unroll 4
    for (int k = 0; k < 288; k++) acc += crow[k] * W1[k * 128 + tid];
    acc += b1[tid];
    if (bfm) ((bf16*)out)[2050 + g * 128 + tid] = __float2bfloat16(acc);
    else     ((float*)out)[2050 + g * 128 + tid] = acc;
    float r = fmaxf(acc, 0.f);
    float p0 = r * W2[tid * 2 + 0];
    float p1 = r * W2[tid * 2 + 1];
    for (int o = 32; o > 0; o >>= 1) {
        p0 += __shfl_down(p0, o);
        p1 += __shfl_down(p1, o);
    }
    if ((tid & 63) == 0) { red[(tid >> 6) * 2 + 0] = p0; red[(tid >> 6) * 2 + 1] = p1; }
    __syncthreads();
    if (tid == 0) {
        float l0 = red[0] + red[2] + b2[0];
        float l1 = red[1] + red[3] + b2[1];
        float m = fmaxf(l0, l1);
        float lse = m + logf(expf(l0 - m) + expf(l1 - m));
        float g0 = l0 - lse, g1 = l1 - lse;
        if (bfm) {
            ((bf16*)out)[g * 2 + 0] = __float2bfloat16(g0);
            ((bf16*)out)[g * 2 + 1] = __float2bfloat16(g1);
        } else {
            ((float*)out)[g * 2 + 0] = g0;
            ((float*)out)[g * 2 + 1] = g1;
        }
        int yy = y[g];
        atomicAdd(&scal[0], (yy == 0) ? -g0 : -g1);
        int pred = (l1 > l0) ? 1 : 0;
        if (pred == yy) atomicAdd(&scal[1], 1.0f);
    }
}

__global__ void k_fin(const float* __restrict__ scal, void* __restrict__ out,
                      const int* __restrict__ flag) {
    if (threadIdx.x == 0 && blockIdx.x == 0) {
        if (flag[0]) {
            ((bf16*)out)[2048] = __float2bfloat16(scal[0] / (float)GG);
            ((bf16*)out)[2049] = __float2bfloat16(scal[1] / (float)GG);
        } else {
            ((float*)out)[2048] = scal[0] / (float)GG;
            ((float*)out)[2049] = scal[1] / (float)GG;
        }
    }
}

extern "C" void kernel_launch(void* const* d_in, const int* in_sizes, int n_in,
                              void* d_out, int out_size, void* d_ws, size_t ws_size,
                              hipStream_t stream) {
    const void* x[3]  = {d_in[0], d_in[3], d_in[6]};
    const int*  ei[3] = {(const int*)d_in[1], (const int*)d_in[4], (const int*)d_in[7]};
    const int*  y     = (const int*)d_in[9];
    const void* Wc[3] = {d_in[10], d_in[12], d_in[14]};
    const void* bc[3] = {d_in[11], d_in[13], d_in[15]};

    // workspace carve-up (f32 words):
    // dis[N] | bufA[N*32] | bufB[N*32] | cat[G*288] | scal[2] | flag[1] | wf[43490]
    float* dis  = (float*)d_ws;
    float* bufA = dis + NN;
    float* bufB = bufA + (size_t)NN * CC;
    float* cat  = bufB + (size_t)NN * CC;
    float* scal = cat + (size_t)GG * 288;
    int*   flag = (int*)(scal + 2);
    float* wf   = (float*)(flag + 1);
    // wf offsets
    float* fWc0 = wf;            // 4096
    float* fbc0 = fWc0 + 4096;   // 32
    float* fWc1 = fbc0 + 32;     // 1024
    float* fbc1 = fWc1 + 1024;   // 32
    float* fWc2 = fbc1 + 32;     // 1024
    float* fbc2 = fWc2 + 1024;   // 32
    float* fW1  = fbc2 + 32;     // 36864
    float* fb1  = fW1 + 36864;   // 128
    float* fW2  = fb1 + 128;     // 256
    float* fb2  = fW2 + 256;     // 2

    size_t need = (size_t)(fb2 + 2 - (float*)d_ws) * sizeof(float);
    if (ws_size < need) return;   // starved: leave out zero as a diagnostic

    k_probe<<<1, 128, 0, stream>>>((const unsigned short*)x[0], flag);

    k_cvt<<<(4096 + 255) / 256, 256, 0, stream>>>(Wc[0], fWc0, 4096, flag);
    k_cvt<<<1, 256, 0, stream>>>(bc[0], fbc0, 32, flag);
    k_cvt<<<(1024 + 255) / 256, 256, 0, stream>>>(Wc[1], fWc1, 1024, flag);
    k_cvt<<<1, 256, 0, stream>>>(bc[1], fbc1, 32, flag);
    k_cvt<<<(1024 + 255) / 256, 256, 0, stream>>>(Wc[2], fWc2, 1024, flag);
    k_cvt<<<1, 256, 0, stream>>>(bc[2], fbc2, 32, flag);
    k_cvt<<<(36864 + 255) / 256, 256, 0, stream>>>(d_in[16], fW1, 36864, flag);
    k_cvt<<<1, 256, 0, stream>>>(d_in[17], fb1, 128, flag);
    k_cvt<<<1, 256, 0, stream>>>(d_in[18], fW2, 256, flag);
    k_cvt<<<1, 256, 0, stream>>>(d_in[19], fb2, 2, flag);

    hipMemsetAsync(scal, 0, 2 * sizeof(float), stream);

    for (int b = 0; b < 3; b++) {
        hipMemsetAsync(dis, 0, NN * sizeof(float), stream);
        k_deg<<<EE / 256, 256, 0, stream>>>(ei[b], dis);
        k_dis<<<NN / 256, 256, 0, stream>>>(dis);
        const float* fW[3] = {fWc0, fWc1, fWc2};
        const float* fb[3] = {fbc0, fbc1, fbc2};
        for (int l = 0; l < 3; l++) {
            if (l == 0) k_gemm0<<<NN / 8, 256, 0, stream>>>(x[b], fW[0], bufA, flag);
            else        k_gemm32<<<NN / 8, 256, 0, stream>>>(bufB, fW[l], bufA);
            hipMemsetAsync(bufB, 0, (size_t)NN * CC * sizeof(float), stream);
            k_agg<<<(EE / 256) * 32, 256, 0, stream>>>(ei[b], dis, bufA, bufB);
            k_final<<<NN * CC / 256, 256, 0, stream>>>(bufB, bufA, dis, fb[l], cat, b * 96 + l * 32);
        }
    }

    k_head<<<GG, 128, 0, stream>>>(cat, fW1, fb1, fW2, fb2, y, d_out, scal, flag);
    k_fin<<<1, 64, 0, stream>>>(scal, d_out, flag);
}

// Round 3
// 2446.538 us; speedup vs baseline: 2.1553x; 2.1553x over previous
//
#include <hip/hip_runtime.h>
#include <hip/hip_bf16.h>

// Problem constants (fixed by the reference)
#define NN  131072      // nodes
#define GG  1024        // graphs
#define NPG 128         // nodes per graph
#define EE  4194304     // edges
#define DD  128         // input feature dim
#define CC  32          // per-layer conv width

typedef __hip_bfloat16 bf16;

// ---- dtype probe: classify x0's first 128 uint16s (bf16 vs f32 buffer) ----
__global__ void k_probe(const unsigned short* __restrict__ x, int* __restrict__ flag) {
    unsigned short u = x[threadIdx.x];
    int e = (u >> 7) & 0xFF;
    int q = (e >= 0x70 && e <= 0x85) ? 1 : 0;   // |v| in [2^-15, 2^6]
    unsigned long long m = __ballot(q);
    __shared__ int cnt[2];
    if ((threadIdx.x & 63) == 0) cnt[threadIdx.x >> 6] = __popcll(m);
    __syncthreads();
    if (threadIdx.x == 0) flag[0] = (cnt[0] + cnt[1] >= 96) ? 1 : 0;  // 1 = bf16 mode
}

// ---- convert a weight tensor to f32 scratch (dual dtype) ----
__global__ void k_cvt(const void* __restrict__ in, float* __restrict__ out, int n,
                      const int* __restrict__ flag) {
    int i = blockIdx.x * 256 + threadIdx.x;
    if (i >= n) return;
    if (flag[0]) out[i] = __bfloat162float(((const bf16*)in)[i]);
    else         out[i] = ((const float*)in)[i];
}

// ================= CSR build =================

// counts[dst]++ over all edges
__global__ void k_count(const int* __restrict__ ei, int* __restrict__ cnt) {
    int e = blockIdx.x * 256 + threadIdx.x;           // grid exact EE/256
    atomicAdd(&cnt[ei[EE + e]], 1);
}

// per-block exclusive scan of cnt -> rowptr, block sums -> aux[512]
__global__ void __launch_bounds__(256) k_scan1(const int* __restrict__ cnt,
                                               int* __restrict__ rowptr,
                                               int* __restrict__ aux) {
    __shared__ int s[256];
    int i = blockIdx.x * 256 + threadIdx.x;
    int v = cnt[i];
    s[threadIdx.x] = v;
    __syncthreads();
    for (int o = 1; o < 256; o <<= 1) {
        int t = (threadIdx.x >= o) ? s[threadIdx.x - o] : 0;
        __syncthreads();
        s[threadIdx.x] += t;
        __syncthreads();
    }
    rowptr[i] = s[threadIdx.x] - v;                   // block-local exclusive
    if (threadIdx.x == 255) aux[blockIdx.x] = s[255];
}

// single-block exclusive scan of aux[512]; aux[512] = total
__global__ void __launch_bounds__(512) k_scan2(int* __restrict__ aux) {
    __shared__ int s[512];
    int v = aux[threadIdx.x];
    s[threadIdx.x] = v;
    __syncthreads();
    for (int o = 1; o < 512; o <<= 1) {
        int t = (threadIdx.x >= o) ? s[threadIdx.x - o] : 0;
        __syncthreads();
        s[threadIdx.x] += t;
        __syncthreads();
    }
    aux[threadIdx.x] = s[threadIdx.x] - v;
    if (threadIdx.x == 511) aux[512] = s[511];
}

// add block offsets; derive dis = rsqrt(deg+1); rowptr[NN] = E
__global__ void k_scan3(int* __restrict__ rowptr, const int* __restrict__ aux,
                        const int* __restrict__ cnt, float* __restrict__ dis) {
    int i = blockIdx.x * 256 + threadIdx.x;
    rowptr[i] += aux[blockIdx.x];
    dis[i] = rsqrtf((float)cnt[i] + 1.0f);
    if (i == NN - 1) rowptr[NN] = aux[512];
}

// scatter edges into CSR; fused: mark srcs of seed-dst edges for the frontier
__global__ void k_fill(const int* __restrict__ ei, const int* __restrict__ rowptr,
                       int* __restrict__ cur, int* __restrict__ col,
                       int* __restrict__ mark) {
    int e = blockIdx.x * 256 + threadIdx.x;
    int s = ei[e], d = ei[EE + e];
    int pos = rowptr[d] + atomicAdd(&cur[d], 1);
    col[pos] = s;
    if ((d & (NPG - 1)) == 0) mark[s] = 1;
}

__global__ void k_seedmark(int* __restrict__ mark) {
    int g = blockIdx.x * 256 + threadIdx.x;
    if (g < GG) mark[g * NPG] = 1;
}

__global__ void k_compact(const int* __restrict__ mark, int* __restrict__ flist,
                          int* __restrict__ fcnt) {
    int i = blockIdx.x * 256 + threadIdx.x;
    if (mark[i]) flist[atomicAdd(fcnt, 1)] = i;
}

// ================= GEMMs =================

// h = x(N x 128, dtype per flag) @ W(f32 128 x 32) -> f32 N x 32
__global__ void __launch_bounds__(256) k_gemm0(const void* __restrict__ x,
                                               const float* __restrict__ W,
                                               float* __restrict__ h,
                                               const int* __restrict__ flag) {
    __shared__ float Wl[DD * CC];
    __shared__ float xl[8 * DD];
    int tid = threadIdx.x;
    int bfm = flag[0];
    for (int t = tid; t < DD * CC; t += 256) Wl[t] = W[t];
    long rowbase = (long)blockIdx.x * 8;
    if (bfm) {
        const bf16* xp = (const bf16*)x;
        for (int t = tid; t < 8 * DD; t += 256) xl[t] = __bfloat162float(xp[rowbase * DD + t]);
    } else {
        const float* xp = (const float*)x;
        for (int t = tid; t < 8 * DD; t += 256) xl[t] = xp[rowbase * DD + t];
    }
    __syncthreads();
    int r = tid >> 5, c = tid & 31;
    float acc = 0.f;
    #pragma unroll 8
    for (int k = 0; k < DD; k++) acc += xl[r * DD + k] * Wl[k * CC + c];
    h[(rowbase + r) * CC + c] = acc;
}

// full: hout = hin(f32 N x 32) @ W(f32 32 x 32)
__global__ void __launch_bounds__(256) k_gemm32(const float* __restrict__ hin,
                                                const float* __restrict__ W,
                                                float* __restrict__ hout) {
    __shared__ float Wl[CC * CC];
    __shared__ float xl[8 * CC];
    int tid = threadIdx.x;
    for (int t = tid; t < CC * CC; t += 256) Wl[t] = W[t];
    long rowbase = (long)blockIdx.x * 8;
    for (int t = tid; t < 8 * CC; t += 256) xl[t] = hin[rowbase * CC + t];
    __syncthreads();
    int r = tid >> 5, c = tid & 31;
    float acc = 0.f;
    #pragma unroll
    for (int k = 0; k < CC; k++) acc += xl[r * CC + k] * Wl[k * CC + c];
    hout[(rowbase + r) * CC + c] = acc;
}

// list variant: only rows in flist[0..fcnt)
__global__ void __launch_bounds__(256) k_gemm32l(const float* __restrict__ hin,
                                                 const float* __restrict__ W,
                                                 float* __restrict__ hout,
                                                 const int* __restrict__ flist,
                                                 const int* __restrict__ fcnt) {
    int n = *fcnt;
    int base = blockIdx.x * 8;
    if (base >= n) return;                    // uniform per block
    __shared__ float Wl[CC * CC];
    __shared__ float xl[8 * CC];
    __shared__ int rows[8];
    int tid = threadIdx.x;
    for (int t = tid; t < CC * CC; t += 256) Wl[t] = W[t];
    if (tid < 8) rows[tid] = (base + tid < n) ? flist[base + tid] : flist[n - 1];
    __syncthreads();
    int r = tid >> 5, c = tid & 31;
    int row = rows[r];
    xl[tid] = hin[(long)row * CC + c];
    __syncthreads();
    float acc = 0.f;
    #pragma unroll
    for (int k = 0; k < CC; k++) acc += xl[r * CC + k] * Wl[k * CC + c];
    hout[(long)row * CC + c] = acc;           // dup rows write identical values
}

// ================= CSR gather-aggregate (fused normalize+selfloop+bias+tanh) =================
// group of 32 lanes per dst node; acc = sum h[src]*dis[src]; out = tanh((acc + h[d]*dd)*dd + b)

__global__ void __launch_bounds__(256) k_gat_all(const int* __restrict__ rowptr,
                                                 const int* __restrict__ col,
                                                 const float* __restrict__ dis,
                                                 const float* __restrict__ pbuf,
                                                 const float* __restrict__ bias,
                                                 float* __restrict__ hbuf,
                                                 float* __restrict__ cat, int boff) {
    int tid = threadIdx.x;
    int d = blockIdx.x * 8 + (tid >> 5);
    int lane = tid & 31;
    int r0 = rowptr[d], r1 = rowptr[d + 1];
    float acc = 0.f;
    int e = r0;
    for (; e + 1 < r1; e += 2) {
        int s0 = col[e], s1 = col[e + 1];
        float w0 = dis[s0], w1 = dis[s1];
        acc += pbuf[(long)s0 * CC + lane] * w0;
        acc += pbuf[(long)s1 * CC + lane] * w1;
    }
    if (e < r1) { int s = col[e]; acc += pbuf[(long)s * CC + lane] * dis[s]; }
    float dd = dis[d];
    float v = tanhf((acc + pbuf[(long)d * CC + lane] * dd) * dd + bias[lane]);
    hbuf[(long)d * CC + lane] = v;
    if ((d & (NPG - 1)) == 0) cat[(d >> 7) * 288 + boff + lane] = v;
}

__global__ void __launch_bounds__(256) k_gat_list(const int* __restrict__ rowptr,
                                                  const int* __restrict__ col,
                                                  const float* __restrict__ dis,
                                                  const float* __restrict__ pbuf,
                                                  const float* __restrict__ bias,
                                                  float* __restrict__ hbuf,
                                                  float* __restrict__ cat, int boff,
                                                  const int* __restrict__ flist,
                                                  const int* __restrict__ fcnt) {
    int tid = threadIdx.x;
    int idx = blockIdx.x * 8 + (tid >> 5);
    if (idx >= *fcnt) return;
    int d = flist[idx];
    int lane = tid & 31;
    int r0 = rowptr[d], r1 = rowptr[d + 1];
    float acc = 0.f;
    int e = r0;
    for (; e + 1 < r1; e += 2) {
        int s0 = col[e], s1 = col[e + 1];
        float w0 = dis[s0], w1 = dis[s1];
        acc += pbuf[(long)s0 * CC + lane] * w0;
        acc += pbuf[(long)s1 * CC + lane] * w1;
    }
    if (e < r1) { int s = col[e]; acc += pbuf[(long)s * CC + lane] * dis[s]; }
    float dd = dis[d];
    float v = tanhf((acc + pbuf[(long)d * CC + lane] * dd) * dd + bias[lane]);
    hbuf[(long)d * CC + lane] = v;
    if ((d & (NPG - 1)) == 0) cat[(d >> 7) * 288 + boff + lane] = v;
}

// seeds only (d = g*128), writes cat only
__global__ void __launch_bounds__(256) k_gat_seed(const int* __restrict__ rowptr,
                                                  const int* __restrict__ col,
                                                  const float* __restrict__ dis,
                                                  const float* __restrict__ pbuf,
                                                  const float* __restrict__ bias,
                                                  float* __restrict__ cat, int boff) {
    int tid = threadIdx.x;
    int g = blockIdx.x * 8 + (tid >> 5);     // grid exact GG/8
    int d = g * NPG;
    int lane = tid & 31;
    int r0 = rowptr[d], r1 = rowptr[d + 1];
    float acc = 0.f;
    int e = r0;
    for (; e + 1 < r1; e += 2) {
        int s0 = col[e], s1 = col[e + 1];
        float w0 = dis[s0], w1 = dis[s1];
        acc += pbuf[(long)s0 * CC + lane] * w0;
        acc += pbuf[(long)s1 * CC + lane] * w1;
    }
    if (e < r1) { int s = col[e]; acc += pbuf[(long)s * CC + lane] * dis[s]; }
    float dd = dis[d];
    float v = tanhf((acc + pbuf[(long)d * CC + lane] * dd) * dd + bias[lane]);
    cat[g * 288 + boff + lane] = v;
}

// ================= head =================
__global__ void __launch_bounds__(128) k_head(const float* __restrict__ cat,
                                              const float* __restrict__ W1,
                                              const float* __restrict__ b1,
                                              const float* __restrict__ W2,
                                              const float* __restrict__ b2,
                                              const int* __restrict__ y,
                                              void* __restrict__ out,
                                              float* __restrict__ scal,
                                              const int* __restrict__ flag) {
    __shared__ float crow[288];
    __shared__ float red[4];
    int g = blockIdx.x, tid = threadIdx.x;
    int bfm = flag[0];
    for (int t = tid; t < 288; t += 128) crow[t] = cat[g * 288 + t];
    __syncthreads();
    float acc = 0.f;
    #pragma unroll 4
    for (int k = 0; k < 288; k++) acc += crow[k] * W1[k * 128 + tid];
    acc += b1[tid];
    if (bfm) ((bf16*)out)[2050 + g * 128 + tid] = __float2bfloat16(acc);
    else     ((float*)out)[2050 + g * 128 + tid] = acc;
    float r = fmaxf(acc, 0.f);
    float p0 = r * W2[tid * 2 + 0];
    float p1 = r * W2[tid * 2 + 1];
    for (int o = 32; o > 0; o >>= 1) {
        p0 += __shfl_down(p0, o);
        p1 += __shfl_down(p1, o);
    }
    if ((tid & 63) == 0) { red[(tid >> 6) * 2 + 0] = p0; red[(tid >> 6) * 2 + 1] = p1; }
    __syncthreads();
    if (tid == 0) {
        float l0 = red[0] + red[2] + b2[0];
        float l1 = red[1] + red[3] + b2[1];
        float m = fmaxf(l0, l1);
        float lse = m + logf(expf(l0 - m) + expf(l1 - m));
        float g0 = l0 - lse, g1 = l1 - lse;
        if (bfm) {
            ((bf16*)out)[g * 2 + 0] = __float2bfloat16(g0);
            ((bf16*)out)[g * 2 + 1] = __float2bfloat16(g1);
        } else {
            ((float*)out)[g * 2 + 0] = g0;
            ((float*)out)[g * 2 + 1] = g1;
        }
        int yy = y[g];
        atomicAdd(&scal[0], (yy == 0) ? -g0 : -g1);
        int pred = (l1 > l0) ? 1 : 0;
        if (pred == yy) atomicAdd(&scal[1], 1.0f);
    }
}

__global__ void k_fin(const float* __restrict__ scal, void* __restrict__ out,
                      const int* __restrict__ flag) {
    if (threadIdx.x == 0 && blockIdx.x == 0) {
        if (flag[0]) {
            ((bf16*)out)[2048] = __float2bfloat16(scal[0] / (float)GG);
            ((bf16*)out)[2049] = __float2bfloat16(scal[1] / (float)GG);
        } else {
            ((float*)out)[2048] = scal[0] / (float)GG;
            ((float*)out)[2049] = scal[1] / (float)GG;
        }
    }
}

extern "C" void kernel_launch(void* const* d_in, const int* in_sizes, int n_in,
                              void* d_out, int out_size, void* d_ws, size_t ws_size,
                              hipStream_t stream) {
    const void* x[3]  = {d_in[0], d_in[3], d_in[6]};
    const int*  ei[3] = {(const int*)d_in[1], (const int*)d_in[4], (const int*)d_in[7]};
    const int*  y     = (const int*)d_in[9];
    const void* Wc[3] = {d_in[10], d_in[12], d_in[14]};
    const void* bc[3] = {d_in[11], d_in[13], d_in[15]};

    // ---- workspace carve-up ----
    int*   cnt    = (int*)d_ws;                // N      (also CSR cursor)
    int*   rowptr = cnt + NN;                  // N+1
    int*   col    = rowptr + NN + 1;           // E
    int*   mark   = col + EE;                  // N
    int*   flist  = mark + NN;                 // N
    int*   fcnt   = flist + NN;                // 1
    int*   aux    = fcnt + 1;                  // 513
    float* dis    = (float*)(aux + 513);       // N
    float* pbuf   = dis + NN;                  // N*32
    float* hbuf   = pbuf + (size_t)NN * CC;    // N*32
    float* cat    = hbuf + (size_t)NN * CC;    // G*288
    float* scal   = cat + (size_t)GG * 288;    // 2
    int*   flag   = (int*)(scal + 2);          // 1
    float* wf     = (float*)(flag + 1);
    float* fWc0 = wf;            // 4096
    float* fbc0 = fWc0 + 4096;   // 32
    float* fWc1 = fbc0 + 32;     // 1024
    float* fbc1 = fWc1 + 1024;   // 32
    float* fWc2 = fbc1 + 32;     // 1024
    float* fbc2 = fWc2 + 1024;   // 32
    float* fW1  = fbc2 + 32;     // 36864
    float* fb1  = fW1 + 36864;   // 128
    float* fW2  = fb1 + 128;     // 256
    float* fb2  = fW2 + 256;     // 2
    size_t need = (size_t)((char*)(fb2 + 2) - (char*)d_ws);
    if (ws_size < need) return;   // starved: leave out zero as a diagnostic

    k_probe<<<1, 128, 0, stream>>>((const unsigned short*)x[0], flag);
    k_cvt<<<16, 256, 0, stream>>>(Wc[0], fWc0, 4096, flag);
    k_cvt<<<1, 256, 0, stream>>>(bc[0], fbc0, 32, flag);
    k_cvt<<<4, 256, 0, stream>>>(Wc[1], fWc1, 1024, flag);
    k_cvt<<<1, 256, 0, stream>>>(bc[1], fbc1, 32, flag);
    k_cvt<<<4, 256, 0, stream>>>(Wc[2], fWc2, 1024, flag);
    k_cvt<<<1, 256, 0, stream>>>(bc[2], fbc2, 32, flag);
    k_cvt<<<144, 256, 0, stream>>>(d_in[16], fW1, 36864, flag);
    k_cvt<<<1, 256, 0, stream>>>(d_in[17], fb1, 128, flag);
    k_cvt<<<1, 256, 0, stream>>>(d_in[18], fW2, 256, flag);
    k_cvt<<<1, 256, 0, stream>>>(d_in[19], fb2, 2, flag);

    hipMemsetAsync(scal, 0, 2 * sizeof(float), stream);

    const float* fW[3] = {fWc0, fWc1, fWc2};
    const float* fb[3] = {fbc0, fbc1, fbc2};

    for (int b = 0; b < 3; b++) {
        // ---- CSR build (once per branch, reused by 3 layers) ----
        hipMemsetAsync(cnt, 0, NN * sizeof(int), stream);
        k_count<<<EE / 256, 256, 0, stream>>>(ei[b], cnt);
        k_scan1<<<NN / 256, 256, 0, stream>>>(cnt, rowptr, aux);
        k_scan2<<<1, 512, 0, stream>>>(aux);
        k_scan3<<<NN / 256, 256, 0, stream>>>(rowptr, aux, cnt, dis);
        hipMemsetAsync(cnt, 0, NN * sizeof(int), stream);      // cursor
        hipMemsetAsync(mark, 0, NN * sizeof(int), stream);
        hipMemsetAsync(fcnt, 0, sizeof(int), stream);
        k_fill<<<EE / 256, 256, 0, stream>>>(ei[b], rowptr, cnt, col, mark);
        k_seedmark<<<GG / 256, 256, 0, stream>>>(mark);
        k_compact<<<NN / 256, 256, 0, stream>>>(mark, flist, fcnt);

        // ---- layer 1: full graph ----
        k_gemm0<<<NN / 8, 256, 0, stream>>>(x[b], fW[0], pbuf, flag);
        k_gat_all<<<NN / 8, 256, 0, stream>>>(rowptr, col, dis, pbuf, fb[0], hbuf, cat, b * 96);
        // ---- layer 2: frontier only ----
        k_gemm32<<<NN / 8, 256, 0, stream>>>(hbuf, fW[1], pbuf);
        k_gat_list<<<NN / 8, 256, 0, stream>>>(rowptr, col, dis, pbuf, fb[1], hbuf, cat, b * 96 + 32,
                                               flist, fcnt);
        // ---- layer 3: seeds only ----
        k_gemm32l<<<NN / 8, 256, 0, stream>>>(hbuf, fW[2], pbuf, flist, fcnt);
        k_gat_seed<<<GG / 8, 256, 0, stream>>>(rowptr, col, dis, pbuf, fb[2], cat, b * 96 + 64);
    }

    k_head<<<GG, 128, 0, stream>>>(cat, fW1, fb1, fW2, fb2, y, d_out, scal, flag);
    k_fin<<<1, 64, 0, stream>>>(scal, d_out, flag);
}

// Round 4
// 1573.308 us; speedup vs baseline: 3.3515x; 1.5550x over previous
//
#include <hip/hip_runtime.h>
#include <hip/hip_bf16.h>

// Problem constants (fixed by the reference)
#define NN  131072      // nodes
#define GG  1024        // graphs
#define NPG 128         // nodes per graph
#define EE  4194304     // edges
#define DD  128         // input feature dim
#define CC  32          // per-layer conv width
#define NB  512         // CSR buckets (dst>>8), 256 nodes each
#define BTILE 4096      // edges per k_bin block
#define CAP 9600        // k_csr LDS staging capacity (mean 8192, sigma ~90)

typedef __hip_bfloat16 bf16;

// ---- dtype probe: classify x0's first 128 uint16s (bf16 vs f32 buffer) ----
__global__ void k_probe(const unsigned short* __restrict__ x, int* __restrict__ flag) {
    unsigned short u = x[threadIdx.x];
    int e = (u >> 7) & 0xFF;
    int q = (e >= 0x70 && e <= 0x85) ? 1 : 0;
    unsigned long long m = __ballot(q);
    __shared__ int cnt[2];
    if ((threadIdx.x & 63) == 0) cnt[threadIdx.x >> 6] = __popcll(m);
    __syncthreads();
    if (threadIdx.x == 0) flag[0] = (cnt[0] + cnt[1] >= 96) ? 1 : 0;  // 1 = bf16 mode
}

// ---- all weight tensors -> f32 scratch in one launch ----
struct PtrPack { const void* p[10]; };
__global__ void k_cvtall(PtrPack pk, float* __restrict__ wf, const int* __restrict__ flag) {
    int i = blockIdx.x * 256 + threadIdx.x;
    if (i >= 43490) return;
    const int off[11] = {0, 4096, 4128, 5152, 5184, 6208, 6240, 43104, 43232, 43488, 43490};
    int seg = 0;
    #pragma unroll
    for (int k = 1; k < 11; k++) if (i >= off[k]) seg = k;
    int local = i - off[seg];
    if (flag[0]) wf[i] = __bfloat162float(((const bf16*)pk.p[seg])[local]);
    else         wf[i] = ((const float*)pk.p[seg])[local];
}

// ================= bucket-sorted CSR build =================

// global bucket histogram of dst>>8 (LDS-staged)
__global__ void __launch_bounds__(256) k_hist(const int* __restrict__ ei, int* __restrict__ bhist) {
    __shared__ int h[NB];
    int tid = threadIdx.x;
    h[tid] = 0; h[tid + 256] = 0;
    __syncthreads();
    long t0 = (long)blockIdx.x * 8192;
    #pragma unroll 4
    for (int k = 0; k < 32; k++) {
        int e = t0 + k * 256 + tid;
        atomicAdd(&h[ei[EE + e] >> 8], 1);
    }
    __syncthreads();
    atomicAdd(&bhist[tid], h[tid]);
    atomicAdd(&bhist[tid + 256], h[tid + 256]);
}

// exclusive scan of bucket counts -> bbase[513], bcur copy
__global__ void __launch_bounds__(512) k_bscan(const int* __restrict__ bhist,
                                               int* __restrict__ bbase, int* __restrict__ bcur) {
    __shared__ int s[NB];
    int tid = threadIdx.x;
    int v = bhist[tid];
    s[tid] = v;
    __syncthreads();
    for (int o = 1; o < NB; o <<= 1) {
        int t = (tid >= o) ? s[tid - o] : 0;
        __syncthreads();
        s[tid] += t;
        __syncthreads();
    }
    bbase[tid] = s[tid] - v;
    bcur[tid] = s[tid] - v;
    if (tid == NB - 1) bbase[NB] = s[NB - 1];   // = EE
}

// bin edges into bucket-contiguous (dst,src) pair runs, LDS-staged for dense writes
__global__ void __launch_bounds__(512) k_bin(const int* __restrict__ ei,
                                             int* __restrict__ bcur, int2* __restrict__ ebuf) {
    __shared__ int hist[NB], loff[NB], gbase[NB], cur[NB];
    __shared__ int2 staged[BTILE];     // 32 KB
    int tid = threadIdx.x;
    long t0 = (long)blockIdx.x * BTILE;
    hist[tid] = 0;
    __syncthreads();
    int sreg[BTILE / 512], dreg[BTILE / 512];
    #pragma unroll
    for (int k = 0; k < BTILE / 512; k++) {
        int e = t0 + k * 512 + tid;
        sreg[k] = ei[e];
        dreg[k] = ei[EE + e];
        atomicAdd(&hist[dreg[k] >> 8], 1);
    }
    __syncthreads();
    int v = hist[tid];
    loff[tid] = v;
    __syncthreads();
    for (int o = 1; o < NB; o <<= 1) {
        int t = (tid >= o) ? loff[tid - o] : 0;
        __syncthreads();
        loff[tid] += t;
        __syncthreads();
    }
    gbase[tid] = atomicAdd(&bcur[tid], v);   // reserve global run for this block's bucket tid
    cur[tid] = 0;
    int excl = loff[tid] - v;
    __syncthreads();
    loff[tid] = excl;
    __syncthreads();
    #pragma unroll
    for (int k = 0; k < BTILE / 512; k++) {
        int b = dreg[k] >> 8;
        int r = atomicAdd(&cur[b], 1);
        staged[loff[b] + r] = make_int2(dreg[k], sreg[k]);
    }
    __syncthreads();
    #pragma unroll
    for (int k = 0; k < BTILE / 512; k++) {
        int t = k * 512 + tid;
        int2 p = staged[t];
        int b = p.x >> 8;
        ebuf[gbase[b] + (t - loff[b])] = p;   // contiguous runs per bucket
    }
}

// per-bucket counting sort -> col (coalesced), rowptr, dis, seed-neighbor marks
__global__ void __launch_bounds__(256) k_csr(const int* __restrict__ bbase,
                                             const int2* __restrict__ ebuf,
                                             int* __restrict__ rowptr, int* __restrict__ col,
                                             float* __restrict__ dis, int* __restrict__ mark) {
    __shared__ int hist[256], off[256], cur[256];
    __shared__ int lout[CAP];          // 38.4 KB
    int b = blockIdx.x, tid = threadIdx.x;
    int base = bbase[b];
    int n = bbase[b + 1] - base;
    hist[tid] = 0;
    __syncthreads();
    for (int t = tid; t < n; t += 256) {
        int2 p = ebuf[base + t];
        atomicAdd(&hist[p.x & 255], 1);
    }
    __syncthreads();
    int deg = hist[tid];
    off[tid] = deg;
    __syncthreads();
    for (int o = 1; o < 256; o <<= 1) {
        int t = (tid >= o) ? off[tid - o] : 0;
        __syncthreads();
        off[tid] += t;
        __syncthreads();
    }
    int excl = off[tid] - deg;
    int node = b * 256 + tid;
    rowptr[node] = base + excl;
    dis[node] = rsqrtf((float)deg + 1.0f);
    if (b == 0 && tid == 0) rowptr[NN] = EE;
    cur[tid] = 0;
    __syncthreads();
    off[tid] = excl;
    __syncthreads();
    bool fits = (n <= CAP);
    for (int t = tid; t < n; t += 256) {
        int2 p = ebuf[base + t];
        int d8 = p.x & 255;
        int r = off[d8] + atomicAdd(&cur[d8], 1);
        if (fits) lout[r] = p.y;
        else      col[base + r] = p.y;          // rare fallback
        if ((p.x & (NPG - 1)) == 0) mark[p.y] = 1;
    }
    __syncthreads();
    if (fits) for (int t = tid; t < n; t += 256) col[base + t] = lout[t];
}

// seeds + marked in-neighbors -> flist
__global__ void k_compact(const int* __restrict__ mark, int* __restrict__ flist,
                          int* __restrict__ fcnt) {
    int i = blockIdx.x * 256 + threadIdx.x;
    if (((i & (NPG - 1)) == 0) || mark[i]) flist[atomicAdd(fcnt, 1)] = i;
}

// ================= GEMMs =================

__global__ void __launch_bounds__(256) k_gemm0(const void* __restrict__ x,
                                               const float* __restrict__ W,
                                               float* __restrict__ h,
                                               const int* __restrict__ flag) {
    __shared__ float Wl[DD * CC];
    __shared__ float xl[8 * DD];
    int tid = threadIdx.x;
    int bfm = flag[0];
    for (int t = tid; t < DD * CC; t += 256) Wl[t] = W[t];
    long rowbase = (long)blockIdx.x * 8;
    if (bfm) {
        const bf16* xp = (const bf16*)x;
        for (int t = tid; t < 8 * DD; t += 256) xl[t] = __bfloat162float(xp[rowbase * DD + t]);
    } else {
        const float* xp = (const float*)x;
        for (int t = tid; t < 8 * DD; t += 256) xl[t] = xp[rowbase * DD + t];
    }
    __syncthreads();
    int r = tid >> 5, c = tid & 31;
    float acc = 0.f;
    #pragma unroll 8
    for (int k = 0; k < DD; k++) acc += xl[r * DD + k] * Wl[k * CC + c];
    h[(rowbase + r) * CC + c] = acc;
}

__global__ void __launch_bounds__(256) k_gemm32(const float* __restrict__ hin,
                                                const float* __restrict__ W,
                                                float* __restrict__ hout) {
    __shared__ float Wl[CC * CC];
    __shared__ float xl[8 * CC];
    int tid = threadIdx.x;
    for (int t = tid; t < CC * CC; t += 256) Wl[t] = W[t];
    long rowbase = (long)blockIdx.x * 8;
    for (int t = tid; t < 8 * CC; t += 256) xl[t] = hin[rowbase * CC + t];
    __syncthreads();
    int r = tid >> 5, c = tid & 31;
    float acc = 0.f;
    #pragma unroll
    for (int k = 0; k < CC; k++) acc += xl[r * CC + k] * Wl[k * CC + c];
    hout[(rowbase + r) * CC + c] = acc;
}

__global__ void __launch_bounds__(256) k_gemm32l(const float* __restrict__ hin,
                                                 const float* __restrict__ W,
                                                 float* __restrict__ hout,
                                                 const int* __restrict__ flist,
                                                 const int* __restrict__ fcnt) {
    int n = *fcnt;
    int base = blockIdx.x * 8;
    if (base >= n) return;
    __shared__ float Wl[CC * CC];
    __shared__ float xl[8 * CC];
    __shared__ int rows[8];
    int tid = threadIdx.x;
    for (int t = tid; t < CC * CC; t += 256) Wl[t] = W[t];
    if (tid < 8) rows[tid] = (base + tid < n) ? flist[base + tid] : flist[n - 1];
    __syncthreads();
    int r = tid >> 5, c = tid & 31;
    int row = rows[r];
    xl[tid] = hin[(long)row * CC + c];
    __syncthreads();
    float acc = 0.f;
    #pragma unroll
    for (int k = 0; k < CC; k++) acc += xl[r * CC + k] * Wl[k * CC + c];
    hout[(long)row * CC + c] = acc;
}

// ================= CSR gather-aggregate: one WAVE per dst =================
// 64 lanes = 2 edge-slots x 32 features; combine halves via shfl_xor(32).

__device__ __forceinline__ float gat_row(const int* __restrict__ col,
                                         const float* __restrict__ dis,
                                         const float* __restrict__ pbuf,
                                         int r0, int r1, int j, int p) {
    float acc = 0.f;
    int e = r0 + p;
    for (; e + 2 < r1; e += 4) {
        int s0 = col[e], s1 = col[e + 2];
        float w0 = dis[s0], w1 = dis[s1];
        acc += pbuf[(long)s0 * CC + j] * w0;
        acc += pbuf[(long)s1 * CC + j] * w1;
    }
    if (e < r1) { int s = col[e]; acc += pbuf[(long)s * CC + j] * dis[s]; }
    return acc + __shfl_xor(acc, 32);
}

__global__ void __launch_bounds__(256) k_gat_all(const int* __restrict__ rowptr,
                                                 const int* __restrict__ col,
                                                 const float* __restrict__ dis,
                                                 const float* __restrict__ pbuf,
                                                 const float* __restrict__ bias,
                                                 float* __restrict__ hbuf,
                                                 float* __restrict__ cat, int boff) {
    int tid = threadIdx.x;
    int d = blockIdx.x * 4 + (tid >> 6);
    int j = tid & 31, p = (tid >> 5) & 1;
    int r0 = rowptr[d], r1 = rowptr[d + 1];
    float acc = gat_row(col, dis, pbuf, r0, r1, j, p);
    if (p == 0) {
        float dd = dis[d];
        float v = tanhf((acc + pbuf[(long)d * CC + j] * dd) * dd + bias[j]);
        hbuf[(long)d * CC + j] = v;
        if ((d & (NPG - 1)) == 0) cat[(d >> 7) * 288 + boff + j] = v;
    }
}

__global__ void __launch_bounds__(256) k_gat_list(const int* __restrict__ rowptr,
                                                  const int* __restrict__ col,
                                                  const float* __restrict__ dis,
                                                  const float* __restrict__ pbuf,
                                                  const float* __restrict__ bias,
                                                  float* __restrict__ hbuf,
                                                  float* __restrict__ cat, int boff,
                                                  const int* __restrict__ flist,
                                                  const int* __restrict__ fcnt) {
    int tid = threadIdx.x;
    int idx = blockIdx.x * 4 + (tid >> 6);
    if (idx >= *fcnt) return;
    int d = flist[idx];
    int j = tid & 31, p = (tid >> 5) & 1;
    int r0 = rowptr[d], r1 = rowptr[d + 1];
    float acc = gat_row(col, dis, pbuf, r0, r1, j, p);
    if (p == 0) {
        float dd = dis[d];
        float v = tanhf((acc + pbuf[(long)d * CC + j] * dd) * dd + bias[j]);
        hbuf[(long)d * CC + j] = v;
        if ((d & (NPG - 1)) == 0) cat[(d >> 7) * 288 + boff + j] = v;
    }
}

__global__ void __launch_bounds__(256) k_gat_seed(const int* __restrict__ rowptr,
                                                  const int* __restrict__ col,
                                                  const float* __restrict__ dis,
                                                  const float* __restrict__ pbuf,
                                                  const float* __restrict__ bias,
                                                  float* __restrict__ cat, int boff) {
    int tid = threadIdx.x;
    int g = blockIdx.x * 4 + (tid >> 6);
    int d = g * NPG;
    int j = tid & 31, p = (tid >> 5) & 1;
    int r0 = rowptr[d], r1 = rowptr[d + 1];
    float acc = gat_row(col, dis, pbuf, r0, r1, j, p);
    if (p == 0) {
        float dd = dis[d];
        float v = tanhf((acc + pbuf[(long)d * CC + j] * dd) * dd + bias[j]);
        cat[g * 288 + boff + j] = v;
    }
}

// ================= head =================
__global__ void __launch_bounds__(128) k_head(const float* __restrict__ cat,
                                              const float* __restrict__ W1,
                                              const float* __restrict__ b1,
                                              const float* __restrict__ W2,
                                              const float* __restrict__ b2,
                                              const int* __restrict__ y,
                                              void* __restrict__ out,
                                              float* __restrict__ scal,
                                              const int* __restrict__ flag) {
    __shared__ float crow[288];
    __shared__ float red[4];
    int g = blockIdx.x, tid = threadIdx.x;
    int bfm = flag[0];
    for (int t = tid; t < 288; t += 128) crow[t] = cat[g * 288 + t];
    __syncthreads();
    float acc = 0.f;
    #pragma unroll 4
    for (int k = 0; k < 288; k++) acc += crow[k] * W1[k * 128 + tid];
    acc += b1[tid];
    if (bfm) ((bf16*)out)[2050 + g * 128 + tid] = __float2bfloat16(acc);
    else     ((float*)out)[2050 + g * 128 + tid] = acc;
    float r = fmaxf(acc, 0.f);
    float p0 = r * W2[tid * 2 + 0];
    float p1 = r * W2[tid * 2 + 1];
    for (int o = 32; o > 0; o >>= 1) {
        p0 += __shfl_down(p0, o);
        p1 += __shfl_down(p1, o);
    }
    if ((tid & 63) == 0) { red[(tid >> 6) * 2 + 0] = p0; red[(tid >> 6) * 2 + 1] = p1; }
    __syncthreads();
    if (tid == 0) {
        float l0 = red[0] + red[2] + b2[0];
        float l1 = red[1] + red[3] + b2[1];
        float m = fmaxf(l0, l1);
        float lse = m + logf(expf(l0 - m) + expf(l1 - m));
        float g0 = l0 - lse, g1 = l1 - lse;
        if (bfm) {
            ((bf16*)out)[g * 2 + 0] = __float2bfloat16(g0);
            ((bf16*)out)[g * 2 + 1] = __float2bfloat16(g1);
        } else {
            ((float*)out)[g * 2 + 0] = g0;
            ((float*)out)[g * 2 + 1] = g1;
        }
        int yy = y[g];
        atomicAdd(&scal[0], (yy == 0) ? -g0 : -g1);
        int pred = (l1 > l0) ? 1 : 0;
        if (pred == yy) atomicAdd(&scal[1], 1.0f);
    }
}

__global__ void k_fin(const float* __restrict__ scal, void* __restrict__ out,
                      const int* __restrict__ flag) {
    if (threadIdx.x == 0 && blockIdx.x == 0) {
        if (flag[0]) {
            ((bf16*)out)[2048] = __float2bfloat16(scal[0] / (float)GG);
            ((bf16*)out)[2049] = __float2bfloat16(scal[1] / (float)GG);
        } else {
            ((float*)out)[2048] = scal[0] / (float)GG;
            ((float*)out)[2049] = scal[1] / (float)GG;
        }
    }
}

extern "C" void kernel_launch(void* const* d_in, const int* in_sizes, int n_in,
                              void* d_out, int out_size, void* d_ws, size_t ws_size,
                              hipStream_t stream) {
    const void* x[3]  = {d_in[0], d_in[3], d_in[6]};
    const int*  ei[3] = {(const int*)d_in[1], (const int*)d_in[4], (const int*)d_in[7]};
    const int*  y     = (const int*)d_in[9];

    // ---- workspace carve-up ----
    int*   rowptr = (int*)d_ws;                // NN+2 (padded even)
    int*   col    = rowptr + NN + 2;           // EE
    int*   mark   = col + EE;                  // NN
    int*   flist  = mark + NN;                 // NN
    int*   fcnt   = flist + NN;                // 1
    int*   bhist  = fcnt + 1;                  // 512
    int*   bbase  = bhist + 512;               // 513
    int*   bcur   = bbase + 513;               // 512  (running total even)
    float* dis    = (float*)(bcur + 512);      // NN
    float* pbuf   = dis + NN;                  // NN*32   } ebuf (EE int2) overlays
    float* hbuf   = pbuf + (size_t)NN * CC;    // NN*32   } pbuf+hbuf exactly
    int2*  ebuf   = (int2*)pbuf;
    float* cat    = hbuf + (size_t)NN * CC;    // GG*288
    float* scal   = cat + (size_t)GG * 288;    // 2
    int*   flag   = (int*)(scal + 2);          // 1
    float* wf     = (float*)(flag + 1);        // 43490
    float* fWc0 = wf;
    float* fbc0 = wf + 4096;
    float* fWc1 = wf + 4128;
    float* fbc1 = wf + 5152;
    float* fWc2 = wf + 5184;
    float* fbc2 = wf + 6208;
    float* fW1  = wf + 6240;
    float* fb1  = wf + 43104;
    float* fW2  = wf + 43232;
    float* fb2  = wf + 43488;
    size_t need = (size_t)((char*)(wf + 43490) - (char*)d_ws);
    if (ws_size < need) return;   // starved: leave out zero as a diagnostic

    k_probe<<<1, 128, 0, stream>>>((const unsigned short*)x[0], flag);
    PtrPack pk;
    for (int k = 0; k < 10; k++) pk.p[k] = d_in[10 + k];
    k_cvtall<<<170, 256, 0, stream>>>(pk, wf, flag);
    hipMemsetAsync(scal, 0, 2 * sizeof(float), stream);

    const float* fW[3] = {fWc0, fWc1, fWc2};
    const float* fb[3] = {fbc0, fbc1, fbc2};

    for (int b = 0; b < 3; b++) {
        // ---- bucket-sorted CSR build ----
        hipMemsetAsync(bhist, 0, NB * sizeof(int), stream);
        hipMemsetAsync(mark, 0, NN * sizeof(int), stream);
        hipMemsetAsync(fcnt, 0, sizeof(int), stream);
        k_hist<<<512, 256, 0, stream>>>(ei[b], bhist);
        k_bscan<<<1, 512, 0, stream>>>(bhist, bbase, bcur);
        k_bin<<<EE / BTILE, 512, 0, stream>>>(ei[b], bcur, ebuf);
        k_csr<<<NB, 256, 0, stream>>>(bbase, ebuf, rowptr, col, dis, mark);
        k_compact<<<NN / 256, 256, 0, stream>>>(mark, flist, fcnt);

        // ---- layer 1: full graph ----
        k_gemm0<<<NN / 8, 256, 0, stream>>>(x[b], fW[0], pbuf, flag);
        k_gat_all<<<NN / 4, 256, 0, stream>>>(rowptr, col, dis, pbuf, fb[0], hbuf, cat, b * 96);
        // ---- layer 2: frontier only ----
        k_gemm32<<<NN / 8, 256, 0, stream>>>(hbuf, fW[1], pbuf);
        k_gat_list<<<NN / 4, 256, 0, stream>>>(rowptr, col, dis, pbuf, fb[1], hbuf, cat,
                                               b * 96 + 32, flist, fcnt);
        // ---- layer 3: seeds only ----
        k_gemm32l<<<NN / 8, 256, 0, stream>>>(hbuf, fW[2], pbuf, flist, fcnt);
        k_gat_seed<<<GG / 4, 256, 0, stream>>>(rowptr, col, dis, pbuf, fb[2], cat, b * 96 + 64);
    }

    k_head<<<GG, 128, 0, stream>>>(cat, fW1, fb1, fW2, fb2, y, d_out, scal, flag);
    k_fin<<<1, 64, 0, stream>>>(scal, d_out, flag);
}